// Round 11
// baseline (266.362 us; speedup 1.0000x reference)
//
#include <hip/hip_runtime.h>

#define D_MODEL 1024
#define N_TOK   4096
#define HEADS   16
#define FF_DIM  4096
#define SEQ_L   2048

typedef unsigned short u16;
typedef unsigned int   u32;
typedef __bf16 bf16x8 __attribute__((ext_vector_type(8)));
typedef float  f32x4  __attribute__((ext_vector_type(4)));

#define AS1C(p) ((const __attribute__((address_space(1))) void*)(p))
#define AS3(p)  ((__attribute__((address_space(3))) void*)(p))

__device__ __forceinline__ u16 f2bf(float f) {
    union { float f; unsigned u; } c; c.f = f;
    return (u16)((c.u + 0x7fffu + ((c.u >> 16) & 1u)) >> 16);   // RNE
}
__device__ __forceinline__ float bf2f(u16 b) {
    union { unsigned u; float f; } c; c.u = ((unsigned)b) << 16;
    return c.f;
}
__device__ __forceinline__ u32 cvt_pk_bf16(float lo, float hi) {
    u32 r;
    asm("v_cvt_pk_bf16_f32 %0, %1, %2" : "=v"(r) : "v"(lo), "v"(hi));
    return r;
}
__device__ __forceinline__ float fmax3(float a, float b, float c) {
    float r;
    asm("v_max3_f32 %0, %1, %2, %3" : "=v"(r) : "v"(a), "v"(b), "v"(c));
    return r;
}

// ---------------------------------------------------------------------------
// Pipelined 256x256 GEMM (counted-vmcnt, 4 phases/K-tile, double-buffer LDS).
// 512 thr = 8 waves (2M x 4N), wave tile 128x64. XCD-swizzled grid.
// ---------------------------------------------------------------------------
template<int RELU>
__global__ __launch_bounds__(512, 2)
void gemm_pipe(const u16* __restrict__ A, const u16* __restrict__ Bt,
               const float* __restrict__ bias, u16* __restrict__ C,
               int M, int N, int K)
{
    __shared__ u16 As[2][256 * 64];
    __shared__ u16 Bs[2][256 * 64];

    const int tid = threadIdx.x;
    const int wid = tid >> 6, lane = tid & 63;
    const int wr  = wid >> 2, wc = wid & 3;
    const int l15 = lane & 15, l16 = lane >> 4;

    const int nwg = gridDim.x * gridDim.y;
    int bid = blockIdx.y * gridDim.x + blockIdx.x;
    bid = (bid & 7) * (nwg >> 3) + (bid >> 3);
    const int r0 = (bid / gridDim.x) * 256, c0 = (bid % gridDim.x) * 256;

    const u16* Ab = A  + (size_t)r0 * K;
    const u16* Bb = Bt + (size_t)c0 * K;

    f32x4 acc[8][4];
#pragma unroll
    for (int m = 0; m < 8; ++m)
#pragma unroll
        for (int n = 0; n < 4; ++n) acc[m][n] = (f32x4){0.f, 0.f, 0.f, 0.f};

    auto stage = [&](u16* dst, const u16* src, int kbase) {
#pragma unroll
        for (int i = 0; i < 4; ++i) {
            const int r  = i * 64 + (tid >> 3);
            const int gc = (tid & 7) ^ (r & 7);
            __builtin_amdgcn_global_load_lds(AS1C(src + (size_t)r * K + kbase + gc * 8),
                                             AS3(dst + (i * 64 + (wid << 3)) * 64), 16, 0, 0);
        }
    };

    bf16x8 af[4][2], bbA[2][2], bbB[2][2];

    auto ldAf = [&](const u16* sl, int mh) {
#pragma unroll
        for (int m = 0; m < 4; ++m) {
            const int row = wr * 128 + (mh * 4 + m) * 16 + l15;
#pragma unroll
            for (int ks = 0; ks < 2; ++ks) {
                const int ch = (ks * 4 + l16) ^ (row & 7);
                af[m][ks] = *(const bf16x8*)&sl[row * 64 + ch * 8];
            }
        }
    };
    auto ldBf = [&](const u16* sl, int pair, bf16x8 (&bb)[2][2]) {
#pragma unroll
        for (int n = 0; n < 2; ++n) {
            const int row = wc * 64 + (pair * 2 + n) * 16 + l15;
#pragma unroll
            for (int ks = 0; ks < 2; ++ks) {
                const int ch = (ks * 4 + l16) ^ (row & 7);
                bb[n][ks] = *(const bf16x8*)&sl[row * 64 + ch * 8];
            }
        }
    };
    auto mm16 = [&](int mh, int pair, bf16x8 (&bb)[2][2]) {
        __builtin_amdgcn_s_setprio(1);
#pragma unroll
        for (int ks = 0; ks < 2; ++ks)
#pragma unroll
            for (int m = 0; m < 4; ++m)
#pragma unroll
                for (int n = 0; n < 2; ++n)
                    acc[mh * 4 + m][pair * 2 + n] =
                        __builtin_amdgcn_mfma_f32_16x16x32_bf16(af[m][ks], bb[n][ks],
                                                                acc[mh * 4 + m][pair * 2 + n], 0, 0, 0);
        __builtin_amdgcn_s_setprio(0);
    };

    const int nt = K >> 6;
    stage(&As[0][0], Ab, 0);
    stage(&Bs[0][0], Bb, 0);
    stage(&As[1][0], Ab, 64);

    for (int t = 0; t < nt; ++t) {
        u16* Asl = &As[t & 1][0];
        u16* Bsl = &Bs[t & 1][0];
        u16* Aso = &As[t & 1][0];
        u16* Bso = &Bs[(t + 1) & 1][0];

        if (t + 1 < nt) { asm volatile("s_waitcnt vmcnt(4)" ::: "memory"); }
        else            { asm volatile("s_waitcnt vmcnt(0)" ::: "memory"); }
        __builtin_amdgcn_s_barrier();
        ldAf(Asl, 0);
        ldBf(Bsl, 0, bbA);
        if (t + 1 < nt) stage(Bso, Bb, (t + 1) * 64);
        __builtin_amdgcn_s_barrier();
        mm16(0, 0, bbA);
        __builtin_amdgcn_s_barrier();
        ldBf(Bsl, 1, bbB);
        mm16(0, 1, bbB);
        __builtin_amdgcn_s_barrier();
        ldAf(Asl, 1);
        mm16(1, 0, bbA);
        __builtin_amdgcn_s_barrier();
        if (t + 2 < nt) stage(Aso, Ab, (t + 2) * 64);
        mm16(1, 1, bbB);
        __builtin_amdgcn_s_barrier();
    }

#pragma unroll
    for (int n = 0; n < 4; ++n) {
        const int col = c0 + wc * 64 + n * 16 + l15;
        const float bv = bias[col];
#pragma unroll
        for (int m = 0; m < 8; ++m) {
#pragma unroll
            for (int r = 0; r < 4; ++r) {
                const size_t row = (size_t)(r0 + wr * 128 + m * 16 + l16 * 4 + r);
                float v = acc[m][n][r] + bv;
                if (RELU) v = fmaxf(v, 0.f);
                C[row * N + col] = f2bf(v);
            }
        }
    }
}

// ---------------------------------------------------------------------------
// Pipelined 128x128 GEMM (counted-vmcnt, 2 barriers/K-tile, dbuf LDS).
// 512 thr = 8 waves (2M x 4N), wave tile 64x32. For N=1024 GEMMs (grid 256).
// ---------------------------------------------------------------------------
template<int RELU>
__global__ __launch_bounds__(512, 2)
void gemm_pipe128(const u16* __restrict__ A, const u16* __restrict__ Bt,
                  const float* __restrict__ bias, u16* __restrict__ C,
                  int M, int N, int K)
{
    __shared__ u16 As[2][128 * 64];
    __shared__ u16 Bs[2][128 * 64];

    const int tid = threadIdx.x;
    const int wid = tid >> 6, lane = tid & 63;
    const int wr  = wid >> 2, wc = wid & 3;
    const int l15 = lane & 15, l16 = lane >> 4;

    const int nwg = gridDim.x * gridDim.y;
    int bid = blockIdx.y * gridDim.x + blockIdx.x;
    bid = (bid & 7) * (nwg >> 3) + (bid >> 3);
    const int r0 = (bid / gridDim.x) * 128, c0 = (bid % gridDim.x) * 128;

    const u16* Ab = A  + (size_t)r0 * K;
    const u16* Bb = Bt + (size_t)c0 * K;

    f32x4 acc[4][2];
#pragma unroll
    for (int m = 0; m < 4; ++m)
#pragma unroll
        for (int n = 0; n < 2; ++n) acc[m][n] = (f32x4){0.f, 0.f, 0.f, 0.f};

    auto stage = [&](u16* dst, const u16* src, int kbase) {
#pragma unroll
        for (int i = 0; i < 2; ++i) {
            const int r  = i * 64 + (tid >> 3);
            const int gc = (tid & 7) ^ (r & 7);
            __builtin_amdgcn_global_load_lds(AS1C(src + (size_t)r * K + kbase + gc * 8),
                                             AS3(dst + (i * 64 + (wid << 3)) * 64), 16, 0, 0);
        }
    };

    const int nt = K >> 6;
    stage(&As[0][0], Ab, 0);  stage(&Bs[0][0], Bb, 0);
    stage(&As[1][0], Ab, 64); stage(&Bs[1][0], Bb, 64);

    for (int t = 0; t < nt; ++t) {
        const u16* Asl = &As[t & 1][0];
        const u16* Bsl = &Bs[t & 1][0];

        if (t + 1 < nt) { asm volatile("s_waitcnt vmcnt(4)" ::: "memory"); }
        else            { asm volatile("s_waitcnt vmcnt(0)" ::: "memory"); }
        __builtin_amdgcn_s_barrier();

        bf16x8 af[4][2], bb[2][2];
#pragma unroll
        for (int m = 0; m < 4; ++m) {
            const int row = wr * 64 + m * 16 + l15;
#pragma unroll
            for (int ks = 0; ks < 2; ++ks) {
                const int ch = (ks * 4 + l16) ^ (row & 7);
                af[m][ks] = *(const bf16x8*)&Asl[row * 64 + ch * 8];
            }
        }
#pragma unroll
        for (int n = 0; n < 2; ++n) {
            const int row = wc * 32 + n * 16 + l15;
#pragma unroll
            for (int ks = 0; ks < 2; ++ks) {
                const int ch = (ks * 4 + l16) ^ (row & 7);
                bb[n][ks] = *(const bf16x8*)&Bsl[row * 64 + ch * 8];
            }
        }
        __builtin_amdgcn_s_setprio(1);
#pragma unroll
        for (int ks = 0; ks < 2; ++ks)
#pragma unroll
            for (int m = 0; m < 4; ++m)
#pragma unroll
                for (int n = 0; n < 2; ++n)
                    acc[m][n] = __builtin_amdgcn_mfma_f32_16x16x32_bf16(af[m][ks], bb[n][ks], acc[m][n], 0, 0, 0);
        __builtin_amdgcn_s_setprio(0);
        __builtin_amdgcn_s_barrier();

        if (t + 2 < nt) {
            stage(&As[t & 1][0], Ab, (t + 2) * 64);
            stage(&Bs[t & 1][0], Bb, (t + 2) * 64);
        }
    }

#pragma unroll
    for (int n = 0; n < 2; ++n) {
        const int col = c0 + wc * 32 + n * 16 + l15;
        const float bv = bias[col];
#pragma unroll
        for (int m = 0; m < 4; ++m) {
#pragma unroll
            for (int r = 0; r < 4; ++r) {
                const size_t row = (size_t)(r0 + wr * 64 + m * 16 + l16 * 4 + r);
                float v = acc[m][n][r] + bv;
                if (RELU) v = fmaxf(v, 0.f);
                C[row * N + col] = f2bf(v);
            }
        }
    }
}

// ---------------------------------------------------------------------------
// MFMA flash attention, SPLIT-S: 1024 blocks = (32 bh) x (16 q0) x (2 s-half).
// Each block: 8 s-tiles of 128, r9 inner loop. Writes per-half normalized O
// (bf16) + (l, m) per q-row. attn_merge recombines.
// ---------------------------------------------------------------------------
__global__ __launch_bounds__(512, 4)
void attn_mfma(const u16* __restrict__ qkv, u16* __restrict__ aop,
               float* __restrict__ lbuf, float* __restrict__ mbuf)
{
    __shared__ u16 Kl[2][128 * 64];   // [s][d] bf16, chunk^(s&7) swizzle
    __shared__ u32 Vt[64 * 64];       // [d][s/2] packed, word^mask(d) swizzle

    const int tid = threadIdx.x;
    const int wid = tid >> 6, lane = tid & 63;
    const int l15 = lane & 15, l16 = lane >> 4;

    int raw = blockIdx.x;                            // 1024 blocks
    const int lin = (raw & 7) * 128 + (raw >> 3);    // XCD-chunked, bijective
    const int bh = lin >> 5, b = bh >> 4, h = bh & 15;
    const int sub = lin & 31;
    const int q0 = (sub & 15) << 7;
    const int sh = sub >> 4;                         // s-half 0/1
    const int sb = sh << 10;                         // s base
    const int ho = h * 64;
    const size_t tb = (size_t)b * SEQ_L;

    const u16* qg = qkv + (tb + q0) * 3072 + ho;
    const u16* kg = qkv + tb * 3072 + 1024 + ho;
    const u16* vg = qkv + tb * 3072 + 2048 + ho;

    const float SC = 0.18033688f;     // (1/8) * log2(e)

    bf16x8 qa[2];
#pragma unroll
    for (int ks = 0; ks < 2; ++ks) {
        union { bf16x8 v; u16 u[8]; u32 w[4]; } a, r;
        a.v = *(const bf16x8*)(qg + (size_t)(wid * 16 + l15) * 3072 + ks * 32 + l16 * 8);
#pragma unroll
        for (int e = 0; e < 4; ++e)
            r.w[e] = cvt_pk_bf16(bf2f(a.u[2 * e]) * SC, bf2f(a.u[2 * e + 1]) * SC);
        qa[ks] = r.v;
    }

    union { bf16x8 v; u32 u[4]; } onesv;
#pragma unroll
    for (int e = 0; e < 4; ++e) onesv.u[e] = 0x3F803F80u;   // bf16 1.0 pairs

    const int sp = lane;
    const int dc = wid;

    auto stageK = [&](int buf, int s0) {
#pragma unroll
        for (int i = 0; i < 2; ++i) {
            const int r  = i * 64 + (tid >> 3);
            const int gc = (tid & 7) ^ (r & 7);
            __builtin_amdgcn_global_load_lds(AS1C(kg + (size_t)(s0 + r) * 3072 + gc * 8),
                                             AS3(&Kl[buf][(i * 64 + wid * 8) * 64]), 16, 0, 0);
        }
    };

    f32x4 oacc[4];
#pragma unroll
    for (int f = 0; f < 4; ++f) oacc[f] = (f32x4){0.f, 0.f, 0.f, 0.f};
    f32x4 lcol = (f32x4){0.f, 0.f, 0.f, 0.f};
    float m_c = -1e30f;

    union { bf16x8 v; u16 u[8]; } ua, ub;
    stageK(0, sb);
    ua.v = *(const bf16x8*)(vg + (size_t)(sb + 2 * sp) * 3072 + dc * 8);
    ub.v = *(const bf16x8*)(vg + (size_t)(sb + 2 * sp + 1) * 3072 + dc * 8);

    const int nt = 1024 / 128;   // 8 tiles per half
    for (int t = 0; t < nt; ++t) {
        const int buf = t & 1;

        asm volatile("s_waitcnt vmcnt(0)" ::: "memory");
#pragma unroll
        for (int e = 0; e < 8; ++e) {
            const int d = dc * 8 + e;
            const int w = sp ^ (((d & 7) << 2) ^ ((d >> 3) << 1));
            Vt[d * 64 + w] = (u32)ua.u[e] | ((u32)ub.u[e] << 16);
        }
        __syncthreads();                               // barrier-1: K(t),V(t) visible

        if (t + 1 < nt) {                              // prefetch under compute
            stageK(buf ^ 1, sb + (t + 1) * 128);
            ua.v = *(const bf16x8*)(vg + (size_t)(sb + (t + 1) * 128 + 2 * sp) * 3072 + dc * 8);
            ub.v = *(const bf16x8*)(vg + (size_t)(sb + (t + 1) * 128 + 2 * sp + 1) * 3072 + dc * 8);
        }

        // S^T = K Q^T
        f32x4 sacc[8];
#pragma unroll
        for (int f = 0; f < 8; ++f) sacc[f] = (f32x4){0.f, 0.f, 0.f, 0.f};
        __builtin_amdgcn_s_setprio(1);
#pragma unroll
        for (int ks = 0; ks < 2; ++ks)
#pragma unroll
            for (int f = 0; f < 8; ++f) {
                const int row = f * 16 + l15;
                const int ch  = (ks * 4 + l16) ^ (row & 7);
                bf16x8 kb = *(const bf16x8*)&Kl[buf][row * 64 + ch * 8];
                sacc[f] = __builtin_amdgcn_mfma_f32_16x16x32_bf16(kb, qa[ks], sacc[f], 0, 0, 0);
            }
        __builtin_amdgcn_s_setprio(0);

        float pm[8];
#pragma unroll
        for (int f = 0; f < 8; ++f)
            pm[f] = fmaxf(fmax3(sacc[f][0], sacc[f][1], sacc[f][2]), sacc[f][3]);
        float mx;
        {
            float t0 = fmax3(pm[0], pm[1], pm[2]);
            float t1 = fmax3(pm[3], pm[4], pm[5]);
            float t2 = fmaxf(pm[6], pm[7]);
            mx = fmax3(t0, t1, t2);
        }
        mx = fmaxf(mx, __shfl_xor(mx, 16));
        mx = fmaxf(mx, __shfl_xor(mx, 32));

        if (__any(mx > m_c + 8.f)) {                   // defer-max
            const float mnew = fmaxf(m_c, mx);
            const float corr = __builtin_exp2f(m_c - mnew);
            m_c = mnew;
#pragma unroll
            for (int r = 0; r < 4; ++r) {
                const float cr = __shfl(corr, l16 * 4 + r);
                lcol[r] *= cr;
#pragma unroll
                for (int f = 0; f < 4; ++f) oacc[f][r] *= cr;
            }
        }

#pragma unroll
        for (int f = 0; f < 8; ++f)
#pragma unroll
            for (int r = 0; r < 4; ++r)
                sacc[f][r] = __builtin_exp2f(sacc[f][r] - m_c);

        u32 pk[8][2];
#pragma unroll
        for (int f = 0; f < 8; ++f) {
            pk[f][0] = cvt_pk_bf16(sacc[f][0], sacc[f][1]);
            pk[f][1] = cvt_pk_bf16(sacc[f][2], sacc[f][3]);
        }

        // O += P V (+ l via ones column), k-order sigma
        __builtin_amdgcn_s_setprio(1);
#pragma unroll
        for (int S = 0; S < 4; ++S) {
            union { bf16x8 v; u32 u[4]; } af;
            af.u[0] = pk[2 * S][0];     af.u[1] = pk[2 * S][1];
            af.u[2] = pk[2 * S + 1][0]; af.u[3] = pk[2 * S + 1][1];
#pragma unroll
            for (int f2 = 0; f2 < 4; ++f2) {
                const int d = f2 * 16 + l15;
                const int swzd = ((d & 7) << 2) ^ ((d >> 3) << 1);
                union { bf16x8 v; uint2 u[2]; } vb;
                vb.u[0] = *(const uint2*)&Vt[d * 64 + ((16 * S + 2 * l16) ^ swzd)];
                vb.u[1] = *(const uint2*)&Vt[d * 64 + ((16 * S + 8 + 2 * l16) ^ swzd)];
                oacc[f2] = __builtin_amdgcn_mfma_f32_16x16x32_bf16(af.v, vb.v, oacc[f2], 0, 0, 0);
            }
            lcol = __builtin_amdgcn_mfma_f32_16x16x32_bf16(af.v, onesv.v, lcol, 0, 0, 0);
        }
        __builtin_amdgcn_s_setprio(0);
        __syncthreads();                               // barrier-2: tile consumed
    }

    // epilogue: per-half normalized O + (l, m) per row
    u16* aoh = aop + (size_t)sh * N_TOK * 1024;
#pragma unroll
    for (int r = 0; r < 4; ++r) {
        const float lv  = lcol[r];
        const float inv = 1.f / lv;
        const int   qrow = q0 + wid * 16 + l16 * 4 + r;
        const size_t row = tb + qrow;
        const float mrow = __shfl(m_c, l16 * 4 + r);   // all lanes participate
#pragma unroll
        for (int f2 = 0; f2 < 4; ++f2)
            aoh[row * 1024 + ho + f2 * 16 + l15] = f2bf(oacc[f2][r] * inv);
        if (l15 == 0) {
            lbuf[sh * 65536 + bh * 2048 + qrow] = lv;
            mbuf[sh * 65536 + bh * 2048 + qrow] = mrow;
        }
    }
}

// ---------------------------------------------------------------------------
// Merge the two s-halves: out = (O1*w1 + O2*w2)/(w1+w2), w_i = l_i*2^(m_i-m).
// ---------------------------------------------------------------------------
__global__ __launch_bounds__(256)
void attn_merge(const u16* __restrict__ aop, const float* __restrict__ lbuf,
                const float* __restrict__ mbuf, u16* __restrict__ ao)
{
    const int t = blockIdx.x, tid = threadIdx.x;
    const int c = tid * 4;
    const int h = tid >> 4;
    const int b = t >> 11, q = t & 2047;
    const int bh = b * 16 + h;
    const int idx = bh * 2048 + q;

    const float l1 = lbuf[idx],         m1 = mbuf[idx];
    const float l2 = lbuf[65536 + idx], m2 = mbuf[65536 + idx];
    const float m  = fmaxf(m1, m2);
    const float w1 = l1 * __builtin_exp2f(m1 - m);
    const float w2 = l2 * __builtin_exp2f(m2 - m);
    const float inv = 1.f / (w1 + w2);
    const float a1 = w1 * inv, a2 = w2 * inv;

    const size_t off = (size_t)t * 1024 + c;
    ushort4 o1 = *(const ushort4*)(aop + off);
    ushort4 o2 = *(const ushort4*)(aop + (size_t)N_TOK * 1024 + off);
    ushort4 o;
    o.x = f2bf(bf2f(o1.x) * a1 + bf2f(o2.x) * a2);
    o.y = f2bf(bf2f(o1.y) * a1 + bf2f(o2.y) * a2);
    o.z = f2bf(bf2f(o1.z) * a1 + bf2f(o2.z) * a2);
    o.w = f2bf(bf2f(o1.w) * a1 + bf2f(o2.w) * a2);
    *(ushort4*)(ao + off) = o;
}

// ---------------------------------------------------------------------------
// Fused residual add + LayerNorm.
//   WF: write f32 out, WB: write bf16 out, XBF: residual input is bf16.
// ---------------------------------------------------------------------------
template<int WF, int WB, int XBF>
__global__ __launch_bounds__(256)
void add_ln(const void* __restrict__ xv, const u16* __restrict__ y,
            const float* __restrict__ g, const float* __restrict__ be,
            float* __restrict__ outf, u16* __restrict__ outb)
{
    __shared__ float red[4];
    const int t = blockIdx.x, tid = threadIdx.x;
    const int c = tid * 4, lane = tid & 63, wv = tid >> 6;

    float xs[4];
    if (XBF) {
        ushort4 a = *(const ushort4*)((const u16*)xv + (size_t)t * D_MODEL + c);
        xs[0] = bf2f(a.x); xs[1] = bf2f(a.y); xs[2] = bf2f(a.z); xs[3] = bf2f(a.w);
    } else {
        float4 a = *(const float4*)((const float*)xv + (size_t)t * D_MODEL + c);
        xs[0] = a.x; xs[1] = a.y; xs[2] = a.z; xs[3] = a.w;
    }
    ushort4 yb = *(const ushort4*)(y + (size_t)t * D_MODEL + c);
    float s[4] = {xs[0] + bf2f(yb.x), xs[1] + bf2f(yb.y),
                  xs[2] + bf2f(yb.z), xs[3] + bf2f(yb.w)};

    float ps = s[0] + s[1] + s[2] + s[3];
#pragma unroll
    for (int off = 32; off > 0; off >>= 1) ps += __shfl_down(ps, off);
    if (lane == 0) red[wv] = ps;
    __syncthreads();
    const float mean = (red[0] + red[1] + red[2] + red[3]) * (1.f / D_MODEL);
    __syncthreads();

    float pv = 0.f;
#pragma unroll
    for (int u = 0; u < 4; ++u) { float d = s[u] - mean; pv += d * d; }
#pragma unroll
    for (int off = 32; off > 0; off >>= 1) pv += __shfl_down(pv, off);
    if (lane == 0) red[wv] = pv;
    __syncthreads();
    const float var = (red[0] + red[1] + red[2] + red[3]) * (1.f / D_MODEL);
    const float inv = rsqrtf(var + 1e-5f);

    float4 g4 = *(const float4*)(g + c);
    float4 b4 = *(const float4*)(be + c);
    float o[4];
#pragma unroll
    for (int u = 0; u < 4; ++u) o[u] = (s[u] - mean) * inv;
    float4 of = {o[0] * g4.x + b4.x, o[1] * g4.y + b4.y, o[2] * g4.z + b4.z, o[3] * g4.w + b4.w};
    if (WF) *(float4*)(outf + (size_t)t * D_MODEL + c) = of;
    if (WB) {
        ushort4 ob = {f2bf(of.x), f2bf(of.y), f2bf(of.z), f2bf(of.w)};
        *(ushort4*)(outb + (size_t)t * D_MODEL + c) = ob;
    }
}

// ---------------------------------------------------------------------------
// Merged preprocessing (unchanged).
// ---------------------------------------------------------------------------
__global__ __launch_bounds__(256)
void prep(const float* __restrict__ Wq, const float* __restrict__ Wk,
          const float* __restrict__ Wv, const float* __restrict__ Wm,
          const float* __restrict__ W1, const float* __restrict__ W2,
          const float* __restrict__ x,
          const float* __restrict__ bq, const float* __restrict__ bk,
          const float* __restrict__ bv,
          u16* __restrict__ wqkv_t, u16* __restrict__ wm_t,
          u16* __restrict__ w1_t, u16* __restrict__ w2_t,
          u16* __restrict__ xb, float* __restrict__ bqkv)
{
    const int blk = blockIdx.x, tid = threadIdx.x;
    if (blk < 3072) {
        __shared__ float T[64][65];
        const float* src; u16* dst; int K, N, tile;
        if (blk < 256)       { src = Wq; dst = wqkv_t;               K = 1024; N = 1024; tile = blk; }
        else if (blk < 512)  { src = Wk; dst = wqkv_t + 1024 * 1024; K = 1024; N = 1024; tile = blk - 256; }
        else if (blk < 768)  { src = Wv; dst = wqkv_t + 2*1024*1024; K = 1024; N = 1024; tile = blk - 512; }
        else if (blk < 1024) { src = Wm; dst = wm_t;                 K = 1024; N = 1024; tile = blk - 768; }
        else if (blk < 2048) { src = W1; dst = w1_t;                 K = 1024; N = 4096; tile = blk - 1024; }
        else                 { src = W2; dst = w2_t;                 K = 4096; N = 1024; tile = blk - 2048; }
        const int ntn = N >> 6;
        const int n0 = (tile % ntn) * 64, k0 = (tile / ntn) * 64;
        const int rr = tid >> 4, cc = (tid & 15) * 4;
#pragma unroll
        for (int u = 0; u < 4; ++u) {
            const float4 v = *(const float4*)(src + (size_t)(k0 + rr + u * 16) * N + n0 + cc);
            T[rr + u * 16][cc + 0] = v.x; T[rr + u * 16][cc + 1] = v.y;
            T[rr + u * 16][cc + 2] = v.z; T[rr + u * 16][cc + 3] = v.w;
        }
        __syncthreads();
#pragma unroll
        for (int u = 0; u < 4; ++u) {
            const int n = rr + u * 16;
            ushort4 o;
            o.x = f2bf(T[cc + 0][n]); o.y = f2bf(T[cc + 1][n]);
            o.z = f2bf(T[cc + 2][n]); o.w = f2bf(T[cc + 3][n]);
            *(ushort4*)(dst + (size_t)(n0 + n) * K + k0 + cc) = o;
        }
    } else if (blk < 3072 + 4096) {
        const int i = (blk - 3072) * 1024 + tid * 4;
        float4 v = *(const float4*)(x + i);
        ushort4 o = {f2bf(v.x), f2bf(v.y), f2bf(v.z), f2bf(v.w)};
        *(ushort4*)(xb + i) = o;
    } else {
#pragma unroll
        for (int u = 0; u < 12; ++u) {
            const int i = u * 256 + tid;
            bqkv[i] = i < 1024 ? bq[i] : (i < 2048 ? bk[i - 1024] : bv[i - 2048]);
        }
    }
}

// ---------------------------------------------------------------------------
extern "C" void kernel_launch(void* const* d_in, const int* in_sizes, int n_in,
                              void* d_out, int out_size, void* d_ws, size_t ws_size,
                              hipStream_t stream)
{
    (void)in_sizes; (void)n_in; (void)out_size; (void)ws_size;

    const float* x   = (const float*)d_in[0];
    const float* Wq  = (const float*)d_in[1];
    const float* bq  = (const float*)d_in[2];
    const float* Wk  = (const float*)d_in[3];
    const float* bk  = (const float*)d_in[4];
    const float* Wv  = (const float*)d_in[5];
    const float* bv  = (const float*)d_in[6];
    const float* Wm  = (const float*)d_in[7];
    const float* bm  = (const float*)d_in[8];
    const float* W1  = (const float*)d_in[9];
    const float* b1  = (const float*)d_in[10];
    const float* W2  = (const float*)d_in[11];
    const float* b2  = (const float*)d_in[12];
    const float* g1  = (const float*)d_in[13];
    const float* be1 = (const float*)d_in[14];
    const float* g2  = (const float*)d_in[15];
    const float* be2 = (const float*)d_in[16];
    float* out = (float*)d_out;

    char* base = (char*)d_ws;
    const size_t MB = 1u << 20;
    u16*   wqkv_t = (u16*)(base);              //  0..6MB : [3072][1024]
    u16*   wm_t   = (u16*)(base + 6 * MB);     //  6..8MB
    u16*   w1_t   = (u16*)(base + 8 * MB);     //  8..16MB: [4096][1024]
    u16*   w2_t   = (u16*)(base + 16 * MB);    // 16..24MB: [1024][4096]
    float* bqkv   = (float*)(base + 24 * MB);
    u16*   xb     = (u16*)(base + 25 * MB);    // 25..33MB (dead after QKV)
    u16*   qkv    = (u16*)(base + 33 * MB);    // 33..57MB [4096][3072]
    u16*   aop    = (u16*)(base + 57 * MB);    // 57..73MB: 2 x [4096][1024]
    u16*   aof    = (u16*)(base + 33 * MB);    // alias qkv (dead after attn)
    u16*   f1     = (u16*)(base + 33 * MB);    // alias (dead after Wm)
    u16*   msg    = (u16*)(base + 25 * MB);    // alias xb
    u16*   ffn    = (u16*)(base + 25 * MB);
    u16*   hb     = (u16*)(base + 73 * MB);    // 73..81MB
    float* lbuf   = (float*)(base + 81 * MB);  // 2 x 65536 f32
    float* mbuf   = (float*)(base + 81 * MB + 512 * 1024);

    dim3 blk(256);
    prep<<<dim3(3072 + 4096 + 1), blk, 0, stream>>>(Wq, Wk, Wv, Wm, W1, W2, x,
                                                    bq, bk, bv,
                                                    wqkv_t, wm_t, w1_t, w2_t, xb, bqkv);

    gemm_pipe<0><<<dim3(12, 16), dim3(512), 0, stream>>>(xb, wqkv_t, bqkv, qkv, N_TOK, 3072, 1024);
    attn_mfma<<<dim3(1024), dim3(512), 0, stream>>>(qkv, aop, lbuf, mbuf);
    attn_merge<<<dim3(N_TOK), blk, 0, stream>>>(aop, lbuf, mbuf, aof);
    gemm_pipe128<0><<<dim3(8, 32), dim3(512), 0, stream>>>(aof, wm_t, bm, msg, N_TOK, 1024, 1024);
    add_ln<0, 1, 0><<<dim3(N_TOK), blk, 0, stream>>>(x, msg, g1, be1, nullptr, hb);
    gemm_pipe<1><<<dim3(16, 16), dim3(512), 0, stream>>>(hb, w1_t, b1, f1, N_TOK, FF_DIM, 1024);
    gemm_pipe128<0><<<dim3(8, 32), dim3(512), 0, stream>>>(f1, w2_t, b2, ffn, N_TOK, 1024, FF_DIM);
    add_ln<1, 0, 1><<<dim3(N_TOK), blk, 0, stream>>>(hb, ffn, g2, be2, out, nullptr);
}

// Round 12
// 249.250 us; speedup vs baseline: 1.0687x; 1.0687x over previous
//
#include <hip/hip_runtime.h>

#define D_MODEL 1024
#define N_TOK   4096
#define HEADS   16
#define FF_DIM  4096
#define SEQ_L   2048

typedef unsigned short u16;
typedef unsigned int   u32;
typedef __bf16 bf16x8 __attribute__((ext_vector_type(8)));
typedef float  f32x4  __attribute__((ext_vector_type(4)));

#define AS1C(p) ((const __attribute__((address_space(1))) void*)(p))
#define AS3(p)  ((__attribute__((address_space(3))) void*)(p))

__device__ __forceinline__ u16 f2bf(float f) {
    union { float f; unsigned u; } c; c.f = f;
    return (u16)((c.u + 0x7fffu + ((c.u >> 16) & 1u)) >> 16);   // RNE
}
__device__ __forceinline__ float bf2f(u16 b) {
    union { unsigned u; float f; } c; c.u = ((unsigned)b) << 16;
    return c.f;
}
__device__ __forceinline__ u32 cvt_pk_bf16(float lo, float hi) {
    u32 r;
    asm("v_cvt_pk_bf16_f32 %0, %1, %2" : "=v"(r) : "v"(lo), "v"(hi));
    return r;
}
__device__ __forceinline__ float fmax3(float a, float b, float c) {
    float r;
    asm("v_max3_f32 %0, %1, %2, %3" : "=v"(r) : "v"(a), "v"(b), "v"(c));
    return r;
}

// ---------------------------------------------------------------------------
// Pipelined 256x256 GEMM (counted-vmcnt, 4 phases/K-tile, double-buffer LDS).
// 512 thr = 8 waves (2M x 4N), wave tile 128x64. XCD-swizzled grid.
// ---------------------------------------------------------------------------
template<int RELU>
__global__ __launch_bounds__(512, 2)
void gemm_pipe(const u16* __restrict__ A, const u16* __restrict__ Bt,
               const float* __restrict__ bias, u16* __restrict__ C,
               int M, int N, int K)
{
    __shared__ u16 As[2][256 * 64];
    __shared__ u16 Bs[2][256 * 64];

    const int tid = threadIdx.x;
    const int wid = tid >> 6, lane = tid & 63;
    const int wr  = wid >> 2, wc = wid & 3;
    const int l15 = lane & 15, l16 = lane >> 4;

    const int nwg = gridDim.x * gridDim.y;
    int bid = blockIdx.y * gridDim.x + blockIdx.x;
    bid = (bid & 7) * (nwg >> 3) + (bid >> 3);
    const int r0 = (bid / gridDim.x) * 256, c0 = (bid % gridDim.x) * 256;

    const u16* Ab = A  + (size_t)r0 * K;
    const u16* Bb = Bt + (size_t)c0 * K;

    f32x4 acc[8][4];
#pragma unroll
    for (int m = 0; m < 8; ++m)
#pragma unroll
        for (int n = 0; n < 4; ++n) acc[m][n] = (f32x4){0.f, 0.f, 0.f, 0.f};

    auto stage = [&](u16* dst, const u16* src, int kbase) {
#pragma unroll
        for (int i = 0; i < 4; ++i) {
            const int r  = i * 64 + (tid >> 3);
            const int gc = (tid & 7) ^ (r & 7);
            __builtin_amdgcn_global_load_lds(AS1C(src + (size_t)r * K + kbase + gc * 8),
                                             AS3(dst + (i * 64 + (wid << 3)) * 64), 16, 0, 0);
        }
    };

    bf16x8 af[4][2], bbA[2][2], bbB[2][2];

    auto ldAf = [&](const u16* sl, int mh) {
#pragma unroll
        for (int m = 0; m < 4; ++m) {
            const int row = wr * 128 + (mh * 4 + m) * 16 + l15;
#pragma unroll
            for (int ks = 0; ks < 2; ++ks) {
                const int ch = (ks * 4 + l16) ^ (row & 7);
                af[m][ks] = *(const bf16x8*)&sl[row * 64 + ch * 8];
            }
        }
    };
    auto ldBf = [&](const u16* sl, int pair, bf16x8 (&bb)[2][2]) {
#pragma unroll
        for (int n = 0; n < 2; ++n) {
            const int row = wc * 64 + (pair * 2 + n) * 16 + l15;
#pragma unroll
            for (int ks = 0; ks < 2; ++ks) {
                const int ch = (ks * 4 + l16) ^ (row & 7);
                bb[n][ks] = *(const bf16x8*)&sl[row * 64 + ch * 8];
            }
        }
    };
    auto mm16 = [&](int mh, int pair, bf16x8 (&bb)[2][2]) {
        __builtin_amdgcn_s_setprio(1);
#pragma unroll
        for (int ks = 0; ks < 2; ++ks)
#pragma unroll
            for (int m = 0; m < 4; ++m)
#pragma unroll
                for (int n = 0; n < 2; ++n)
                    acc[mh * 4 + m][pair * 2 + n] =
                        __builtin_amdgcn_mfma_f32_16x16x32_bf16(af[m][ks], bb[n][ks],
                                                                acc[mh * 4 + m][pair * 2 + n], 0, 0, 0);
        __builtin_amdgcn_s_setprio(0);
    };

    const int nt = K >> 6;
    stage(&As[0][0], Ab, 0);
    stage(&Bs[0][0], Bb, 0);
    stage(&As[1][0], Ab, 64);

    for (int t = 0; t < nt; ++t) {
        u16* Asl = &As[t & 1][0];
        u16* Bsl = &Bs[t & 1][0];
        u16* Aso = &As[t & 1][0];
        u16* Bso = &Bs[(t + 1) & 1][0];

        if (t + 1 < nt) { asm volatile("s_waitcnt vmcnt(4)" ::: "memory"); }
        else            { asm volatile("s_waitcnt vmcnt(0)" ::: "memory"); }
        __builtin_amdgcn_s_barrier();
        ldAf(Asl, 0);
        ldBf(Bsl, 0, bbA);
        if (t + 1 < nt) stage(Bso, Bb, (t + 1) * 64);
        __builtin_amdgcn_s_barrier();
        mm16(0, 0, bbA);
        __builtin_amdgcn_s_barrier();
        ldBf(Bsl, 1, bbB);
        mm16(0, 1, bbB);
        __builtin_amdgcn_s_barrier();
        ldAf(Asl, 1);
        mm16(1, 0, bbA);
        __builtin_amdgcn_s_barrier();
        if (t + 2 < nt) stage(Aso, Ab, (t + 2) * 64);
        mm16(1, 1, bbB);
        __builtin_amdgcn_s_barrier();
    }

#pragma unroll
    for (int n = 0; n < 4; ++n) {
        const int col = c0 + wc * 64 + n * 16 + l15;
        const float bv = bias[col];
#pragma unroll
        for (int m = 0; m < 8; ++m) {
#pragma unroll
            for (int r = 0; r < 4; ++r) {
                const size_t row = (size_t)(r0 + wr * 128 + m * 16 + l16 * 4 + r);
                float v = acc[m][n][r] + bv;
                if (RELU) v = fmaxf(v, 0.f);
                C[row * N + col] = f2bf(v);
            }
        }
    }
}

// ---------------------------------------------------------------------------
// Pipelined 128x128 GEMM with SPLIT-K over blockIdx.z: each z computes K/nz
// and writes a bf16 partial to C + z*M*N (bias only in z==0). Doubles
// resident blocks/CU for the N=1024 GEMMs (grid 256 -> 512).
// ---------------------------------------------------------------------------
template<int RELU>
__global__ __launch_bounds__(512, 2)
void gemm_pipe128(const u16* __restrict__ A, const u16* __restrict__ Bt,
                  const float* __restrict__ bias, u16* __restrict__ C,
                  int M, int N, int K)
{
    __shared__ u16 As[2][128 * 64];
    __shared__ u16 Bs[2][128 * 64];

    const int tid = threadIdx.x;
    const int wid = tid >> 6, lane = tid & 63;
    const int wr  = wid >> 2, wc = wid & 3;
    const int l15 = lane & 15, l16 = lane >> 4;

    const int nwg = gridDim.x * gridDim.y;
    int bid = blockIdx.y * gridDim.x + blockIdx.x;
    bid = (bid & 7) * (nwg >> 3) + (bid >> 3);
    const int r0 = (bid / gridDim.x) * 128, c0 = (bid % gridDim.x) * 128;

    const int Ks   = K / gridDim.z;              // per-split K
    const int koff = blockIdx.z * Ks;

    const u16* Ab = A  + (size_t)r0 * K + koff;
    const u16* Bb = Bt + (size_t)c0 * K + koff;
    u16*       Cs = C  + (size_t)blockIdx.z * M * N;

    f32x4 acc[4][2];
#pragma unroll
    for (int m = 0; m < 4; ++m)
#pragma unroll
        for (int n = 0; n < 2; ++n) acc[m][n] = (f32x4){0.f, 0.f, 0.f, 0.f};

    auto stage = [&](u16* dst, const u16* src, int kbase) {
#pragma unroll
        for (int i = 0; i < 2; ++i) {
            const int r  = i * 64 + (tid >> 3);
            const int gc = (tid & 7) ^ (r & 7);
            __builtin_amdgcn_global_load_lds(AS1C(src + (size_t)r * K + kbase + gc * 8),
                                             AS3(dst + (i * 64 + (wid << 3)) * 64), 16, 0, 0);
        }
    };

    const int nt = Ks >> 6;
    stage(&As[0][0], Ab, 0);  stage(&Bs[0][0], Bb, 0);
    stage(&As[1][0], Ab, 64); stage(&Bs[1][0], Bb, 64);

    for (int t = 0; t < nt; ++t) {
        const u16* Asl = &As[t & 1][0];
        const u16* Bsl = &Bs[t & 1][0];

        if (t + 1 < nt) { asm volatile("s_waitcnt vmcnt(4)" ::: "memory"); }
        else            { asm volatile("s_waitcnt vmcnt(0)" ::: "memory"); }
        __builtin_amdgcn_s_barrier();

        bf16x8 af[4][2], bb[2][2];
#pragma unroll
        for (int m = 0; m < 4; ++m) {
            const int row = wr * 64 + m * 16 + l15;
#pragma unroll
            for (int ks = 0; ks < 2; ++ks) {
                const int ch = (ks * 4 + l16) ^ (row & 7);
                af[m][ks] = *(const bf16x8*)&Asl[row * 64 + ch * 8];
            }
        }
#pragma unroll
        for (int n = 0; n < 2; ++n) {
            const int row = wc * 32 + n * 16 + l15;
#pragma unroll
            for (int ks = 0; ks < 2; ++ks) {
                const int ch = (ks * 4 + l16) ^ (row & 7);
                bb[n][ks] = *(const bf16x8*)&Bsl[row * 64 + ch * 8];
            }
        }
        __builtin_amdgcn_s_setprio(1);
#pragma unroll
        for (int ks = 0; ks < 2; ++ks)
#pragma unroll
            for (int m = 0; m < 4; ++m)
#pragma unroll
                for (int n = 0; n < 2; ++n)
                    acc[m][n] = __builtin_amdgcn_mfma_f32_16x16x32_bf16(af[m][ks], bb[n][ks], acc[m][n], 0, 0, 0);
        __builtin_amdgcn_s_setprio(0);
        __builtin_amdgcn_s_barrier();

        if (t + 2 < nt) {
            stage(&As[t & 1][0], Ab, (t + 2) * 64);
            stage(&Bs[t & 1][0], Bb, (t + 2) * 64);
        }
    }

    const int addb = (blockIdx.z == 0);
#pragma unroll
    for (int n = 0; n < 2; ++n) {
        const int col = c0 + wc * 32 + n * 16 + l15;
        const float bv = addb ? bias[col] : 0.f;
#pragma unroll
        for (int m = 0; m < 4; ++m) {
#pragma unroll
            for (int r = 0; r < 4; ++r) {
                const size_t row = (size_t)(r0 + wr * 64 + m * 16 + l16 * 4 + r);
                float v = acc[m][n][r] + bv;
                if (RELU) v = fmaxf(v, 0.f);
                Cs[row * N + col] = f2bf(v);
            }
        }
    }
}

// ---------------------------------------------------------------------------
// MFMA flash attention (round-9 proven config): KVBLK=128, dbuf K, single Vt,
// two barriers/tile, ones-column l, setprio around MFMA clusters.
// ---------------------------------------------------------------------------
__global__ __launch_bounds__(512, 4)
void attn_mfma(const u16* __restrict__ qkv, u16* __restrict__ ao)
{
    __shared__ u16 Kl[2][128 * 64];   // [s][d] bf16, chunk^(s&7) swizzle
    __shared__ u32 Vt[64 * 64];       // [d][s/2] packed, word^mask(d) swizzle

    const int tid = threadIdx.x;
    const int wid = tid >> 6, lane = tid & 63;
    const int l15 = lane & 15, l16 = lane >> 4;

    int lin = blockIdx.y * gridDim.x + blockIdx.x;       // 512 blocks
    lin = (lin & 7) * 64 + (lin >> 3);
    const int bh = lin >> 4, b = bh >> 4, h = bh & 15;
    const int q0 = (lin & 15) * 128;
    const int ho = h * 64;
    const size_t tb = (size_t)b * SEQ_L;

    const u16* qg = qkv + (tb + q0) * 3072 + ho;
    const u16* kg = qkv + tb * 3072 + 1024 + ho;
    const u16* vg = qkv + tb * 3072 + 2048 + ho;

    const float SC = 0.18033688f;     // (1/8) * log2(e)

    bf16x8 qa[2];
#pragma unroll
    for (int ks = 0; ks < 2; ++ks) {
        union { bf16x8 v; u16 u[8]; u32 w[4]; } a, r;
        a.v = *(const bf16x8*)(qg + (size_t)(wid * 16 + l15) * 3072 + ks * 32 + l16 * 8);
#pragma unroll
        for (int e = 0; e < 4; ++e)
            r.w[e] = cvt_pk_bf16(bf2f(a.u[2 * e]) * SC, bf2f(a.u[2 * e + 1]) * SC);
        qa[ks] = r.v;
    }

    union { bf16x8 v; u32 u[4]; } onesv;
#pragma unroll
    for (int e = 0; e < 4; ++e) onesv.u[e] = 0x3F803F80u;   // bf16 1.0 pairs

    const int sp = lane;
    const int dc = wid;

    auto stageK = [&](int buf, int s0) {
#pragma unroll
        for (int i = 0; i < 2; ++i) {
            const int r  = i * 64 + (tid >> 3);
            const int gc = (tid & 7) ^ (r & 7);
            __builtin_amdgcn_global_load_lds(AS1C(kg + (size_t)(s0 + r) * 3072 + gc * 8),
                                             AS3(&Kl[buf][(i * 64 + wid * 8) * 64]), 16, 0, 0);
        }
    };

    f32x4 oacc[4];
#pragma unroll
    for (int f = 0; f < 4; ++f) oacc[f] = (f32x4){0.f, 0.f, 0.f, 0.f};
    f32x4 lcol = (f32x4){0.f, 0.f, 0.f, 0.f};
    float m_c = -1e30f;

    union { bf16x8 v; u16 u[8]; } ua, ub;
    stageK(0, 0);
    ua.v = *(const bf16x8*)(vg + (size_t)(2 * sp) * 3072 + dc * 8);
    ub.v = *(const bf16x8*)(vg + (size_t)(2 * sp + 1) * 3072 + dc * 8);

    const int nt = SEQ_L / 128;
    for (int t = 0; t < nt; ++t) {
        const int buf = t & 1;

        asm volatile("s_waitcnt vmcnt(0)" ::: "memory");
#pragma unroll
        for (int e = 0; e < 8; ++e) {
            const int d = dc * 8 + e;
            const int w = sp ^ (((d & 7) << 2) ^ ((d >> 3) << 1));
            Vt[d * 64 + w] = (u32)ua.u[e] | ((u32)ub.u[e] << 16);
        }
        __syncthreads();                               // barrier-1: K(t),V(t) visible

        if (t + 1 < nt) {                              // prefetch under compute
            stageK(buf ^ 1, (t + 1) * 128);
            ua.v = *(const bf16x8*)(vg + (size_t)((t + 1) * 128 + 2 * sp) * 3072 + dc * 8);
            ub.v = *(const bf16x8*)(vg + (size_t)((t + 1) * 128 + 2 * sp + 1) * 3072 + dc * 8);
        }

        // S^T = K Q^T
        f32x4 sacc[8];
#pragma unroll
        for (int f = 0; f < 8; ++f) sacc[f] = (f32x4){0.f, 0.f, 0.f, 0.f};
        __builtin_amdgcn_s_setprio(1);
#pragma unroll
        for (int ks = 0; ks < 2; ++ks)
#pragma unroll
            for (int f = 0; f < 8; ++f) {
                const int row = f * 16 + l15;
                const int ch  = (ks * 4 + l16) ^ (row & 7);
                bf16x8 kb = *(const bf16x8*)&Kl[buf][row * 64 + ch * 8];
                sacc[f] = __builtin_amdgcn_mfma_f32_16x16x32_bf16(kb, qa[ks], sacc[f], 0, 0, 0);
            }
        __builtin_amdgcn_s_setprio(0);

        float pm[8];
#pragma unroll
        for (int f = 0; f < 8; ++f)
            pm[f] = fmaxf(fmax3(sacc[f][0], sacc[f][1], sacc[f][2]), sacc[f][3]);
        float mx;
        {
            float t0 = fmax3(pm[0], pm[1], pm[2]);
            float t1 = fmax3(pm[3], pm[4], pm[5]);
            float t2 = fmaxf(pm[6], pm[7]);
            mx = fmax3(t0, t1, t2);
        }
        mx = fmaxf(mx, __shfl_xor(mx, 16));
        mx = fmaxf(mx, __shfl_xor(mx, 32));

        if (__any(mx > m_c + 8.f)) {                   // defer-max
            const float mnew = fmaxf(m_c, mx);
            const float corr = __builtin_exp2f(m_c - mnew);
            m_c = mnew;
#pragma unroll
            for (int r = 0; r < 4; ++r) {
                const float cr = __shfl(corr, l16 * 4 + r);
                lcol[r] *= cr;
#pragma unroll
                for (int f = 0; f < 4; ++f) oacc[f][r] *= cr;
            }
        }

#pragma unroll
        for (int f = 0; f < 8; ++f)
#pragma unroll
            for (int r = 0; r < 4; ++r)
                sacc[f][r] = __builtin_exp2f(sacc[f][r] - m_c);

        u32 pk[8][2];
#pragma unroll
        for (int f = 0; f < 8; ++f) {
            pk[f][0] = cvt_pk_bf16(sacc[f][0], sacc[f][1]);
            pk[f][1] = cvt_pk_bf16(sacc[f][2], sacc[f][3]);
        }

        // O += P V (+ l via ones column), k-order sigma
        __builtin_amdgcn_s_setprio(1);
#pragma unroll
        for (int S = 0; S < 4; ++S) {
            union { bf16x8 v; u32 u[4]; } af;
            af.u[0] = pk[2 * S][0];     af.u[1] = pk[2 * S][1];
            af.u[2] = pk[2 * S + 1][0]; af.u[3] = pk[2 * S + 1][1];
#pragma unroll
            for (int f2 = 0; f2 < 4; ++f2) {
                const int d = f2 * 16 + l15;
                const int swzd = ((d & 7) << 2) ^ ((d >> 3) << 1);
                union { bf16x8 v; uint2 u[2]; } vb;
                vb.u[0] = *(const uint2*)&Vt[d * 64 + ((16 * S + 2 * l16) ^ swzd)];
                vb.u[1] = *(const uint2*)&Vt[d * 64 + ((16 * S + 8 + 2 * l16) ^ swzd)];
                oacc[f2] = __builtin_amdgcn_mfma_f32_16x16x32_bf16(af.v, vb.v, oacc[f2], 0, 0, 0);
            }
            lcol = __builtin_amdgcn_mfma_f32_16x16x32_bf16(af.v, onesv.v, lcol, 0, 0, 0);
        }
        __builtin_amdgcn_s_setprio(0);
        __syncthreads();                               // barrier-2: tile consumed
    }

#pragma unroll
    for (int r = 0; r < 4; ++r) {
        const float inv = 1.f / lcol[r];
        const size_t row = tb + q0 + wid * 16 + l16 * 4 + r;
#pragma unroll
        for (int f2 = 0; f2 < 4; ++f2)
            ao[row * 1024 + ho + f2 * 16 + l15] = f2bf(oacc[f2][r] * inv);
    }
}

// ---------------------------------------------------------------------------
// Fused residual add + LayerNorm.
//   WF: f32 out, WB: bf16 out, XBF: residual is bf16, Y2: sum two y partials.
// ---------------------------------------------------------------------------
template<int WF, int WB, int XBF, int Y2>
__global__ __launch_bounds__(256)
void add_ln(const void* __restrict__ xv, const u16* __restrict__ y,
            const u16* __restrict__ y2,
            const float* __restrict__ g, const float* __restrict__ be,
            float* __restrict__ outf, u16* __restrict__ outb)
{
    __shared__ float red[4];
    const int t = blockIdx.x, tid = threadIdx.x;
    const int c = tid * 4, lane = tid & 63, wv = tid >> 6;

    float xs[4];
    if (XBF) {
        ushort4 a = *(const ushort4*)((const u16*)xv + (size_t)t * D_MODEL + c);
        xs[0] = bf2f(a.x); xs[1] = bf2f(a.y); xs[2] = bf2f(a.z); xs[3] = bf2f(a.w);
    } else {
        float4 a = *(const float4*)((const float*)xv + (size_t)t * D_MODEL + c);
        xs[0] = a.x; xs[1] = a.y; xs[2] = a.z; xs[3] = a.w;
    }
    ushort4 yb = *(const ushort4*)(y + (size_t)t * D_MODEL + c);
    float s[4] = {xs[0] + bf2f(yb.x), xs[1] + bf2f(yb.y),
                  xs[2] + bf2f(yb.z), xs[3] + bf2f(yb.w)};
    if (Y2) {
        ushort4 y2b = *(const ushort4*)(y2 + (size_t)t * D_MODEL + c);
        s[0] += bf2f(y2b.x); s[1] += bf2f(y2b.y);
        s[2] += bf2f(y2b.z); s[3] += bf2f(y2b.w);
    }

    float ps = s[0] + s[1] + s[2] + s[3];
#pragma unroll
    for (int off = 32; off > 0; off >>= 1) ps += __shfl_down(ps, off);
    if (lane == 0) red[wv] = ps;
    __syncthreads();
    const float mean = (red[0] + red[1] + red[2] + red[3]) * (1.f / D_MODEL);
    __syncthreads();

    float pv = 0.f;
#pragma unroll
    for (int u = 0; u < 4; ++u) { float d = s[u] - mean; pv += d * d; }
#pragma unroll
    for (int off = 32; off > 0; off >>= 1) pv += __shfl_down(pv, off);
    if (lane == 0) red[wv] = pv;
    __syncthreads();
    const float var = (red[0] + red[1] + red[2] + red[3]) * (1.f / D_MODEL);
    const float inv = rsqrtf(var + 1e-5f);

    float4 g4 = *(const float4*)(g + c);
    float4 b4 = *(const float4*)(be + c);
    float o[4];
#pragma unroll
    for (int u = 0; u < 4; ++u) o[u] = (s[u] - mean) * inv;
    float4 of = {o[0] * g4.x + b4.x, o[1] * g4.y + b4.y, o[2] * g4.z + b4.z, o[3] * g4.w + b4.w};
    if (WF) *(float4*)(outf + (size_t)t * D_MODEL + c) = of;
    if (WB) {
        ushort4 ob = {f2bf(of.x), f2bf(of.y), f2bf(of.z), f2bf(of.w)};
        *(ushort4*)(outb + (size_t)t * D_MODEL + c) = ob;
    }
}

// ---------------------------------------------------------------------------
// Merged preprocessing (unchanged).
// ---------------------------------------------------------------------------
__global__ __launch_bounds__(256)
void prep(const float* __restrict__ Wq, const float* __restrict__ Wk,
          const float* __restrict__ Wv, const float* __restrict__ Wm,
          const float* __restrict__ W1, const float* __restrict__ W2,
          const float* __restrict__ x,
          const float* __restrict__ bq, const float* __restrict__ bk,
          const float* __restrict__ bv,
          u16* __restrict__ wqkv_t, u16* __restrict__ wm_t,
          u16* __restrict__ w1_t, u16* __restrict__ w2_t,
          u16* __restrict__ xb, float* __restrict__ bqkv)
{
    const int blk = blockIdx.x, tid = threadIdx.x;
    if (blk < 3072) {
        __shared__ float T[64][65];
        const float* src; u16* dst; int K, N, tile;
        if (blk < 256)       { src = Wq; dst = wqkv_t;               K = 1024; N = 1024; tile = blk; }
        else if (blk < 512)  { src = Wk; dst = wqkv_t + 1024 * 1024; K = 1024; N = 1024; tile = blk - 256; }
        else if (blk < 768)  { src = Wv; dst = wqkv_t + 2*1024*1024; K = 1024; N = 1024; tile = blk - 512; }
        else if (blk < 1024) { src = Wm; dst = wm_t;                 K = 1024; N = 1024; tile = blk - 768; }
        else if (blk < 2048) { src = W1; dst = w1_t;                 K = 1024; N = 4096; tile = blk - 1024; }
        else                 { src = W2; dst = w2_t;                 K = 4096; N = 1024; tile = blk - 2048; }
        const int ntn = N >> 6;
        const int n0 = (tile % ntn) * 64, k0 = (tile / ntn) * 64;
        const int rr = tid >> 4, cc = (tid & 15) * 4;
#pragma unroll
        for (int u = 0; u < 4; ++u) {
            const float4 v = *(const float4*)(src + (size_t)(k0 + rr + u * 16) * N + n0 + cc);
            T[rr + u * 16][cc + 0] = v.x; T[rr + u * 16][cc + 1] = v.y;
            T[rr + u * 16][cc + 2] = v.z; T[rr + u * 16][cc + 3] = v.w;
        }
        __syncthreads();
#pragma unroll
        for (int u = 0; u < 4; ++u) {
            const int n = rr + u * 16;
            ushort4 o;
            o.x = f2bf(T[cc + 0][n]); o.y = f2bf(T[cc + 1][n]);
            o.z = f2bf(T[cc + 2][n]); o.w = f2bf(T[cc + 3][n]);
            *(ushort4*)(dst + (size_t)(n0 + n) * K + k0 + cc) = o;
        }
    } else if (blk < 3072 + 4096) {
        const int i = (blk - 3072) * 1024 + tid * 4;
        float4 v = *(const float4*)(x + i);
        ushort4 o = {f2bf(v.x), f2bf(v.y), f2bf(v.z), f2bf(v.w)};
        *(ushort4*)(xb + i) = o;
    } else {
#pragma unroll
        for (int u = 0; u < 12; ++u) {
            const int i = u * 256 + tid;
            bqkv[i] = i < 1024 ? bq[i] : (i < 2048 ? bk[i - 1024] : bv[i - 2048]);
        }
    }
}

// ---------------------------------------------------------------------------
extern "C" void kernel_launch(void* const* d_in, const int* in_sizes, int n_in,
                              void* d_out, int out_size, void* d_ws, size_t ws_size,
                              hipStream_t stream)
{
    (void)in_sizes; (void)n_in; (void)out_size; (void)ws_size;

    const float* x   = (const float*)d_in[0];
    const float* Wq  = (const float*)d_in[1];
    const float* bq  = (const float*)d_in[2];
    const float* Wk  = (const float*)d_in[3];
    const float* bk  = (const float*)d_in[4];
    const float* Wv  = (const float*)d_in[5];
    const float* bv  = (const float*)d_in[6];
    const float* Wm  = (const float*)d_in[7];
    const float* bm  = (const float*)d_in[8];
    const float* W1  = (const float*)d_in[9];
    const float* b1  = (const float*)d_in[10];
    const float* W2  = (const float*)d_in[11];
    const float* b2  = (const float*)d_in[12];
    const float* g1  = (const float*)d_in[13];
    const float* be1 = (const float*)d_in[14];
    const float* g2  = (const float*)d_in[15];
    const float* be2 = (const float*)d_in[16];
    float* out = (float*)d_out;

    char* base = (char*)d_ws;
    const size_t MB = 1u << 20;
    u16*   wqkv_t = (u16*)(base);              //  0..6MB : [3072][1024]
    u16*   wm_t   = (u16*)(base + 6 * MB);     //  6..8MB
    u16*   w1_t   = (u16*)(base + 8 * MB);     //  8..16MB: [4096][1024]
    u16*   w2_t   = (u16*)(base + 16 * MB);    // 16..24MB: [1024][4096]
    float* bqkv   = (float*)(base + 24 * MB);
    u16*   xb     = (u16*)(base + 25 * MB);    // 25..33MB (dead after QKV)
    u16*   qkv    = (u16*)(base + 33 * MB);    // 33..57MB [4096][3072]
    u16*   ao     = (u16*)(base + 57 * MB);    // 57..65MB
    u16*   msg    = (u16*)(base + 25 * MB);    // partial0 (alias xb, dead)
    u16*   msg2   = (u16*)(base + 33 * MB);    // partial1 (alias qkv, dead post-attn)
    u16*   f1     = (u16*)(base + 33 * MB);    // FFN1 out 33..65 (post-LN1)
    u16*   ffn    = (u16*)(base + 25 * MB);    // partial0 (alias msg, dead post-LN1)
    u16*   ffn2   = (u16*)(base + 73 * MB);    // partial1 73..81MB
    u16*   hb     = (u16*)(base + 65 * MB);    // 65..73MB

    dim3 blk(256);
    prep<<<dim3(3072 + 4096 + 1), blk, 0, stream>>>(Wq, Wk, Wv, Wm, W1, W2, x,
                                                    bq, bk, bv,
                                                    wqkv_t, wm_t, w1_t, w2_t, xb, bqkv);

    gemm_pipe<0><<<dim3(12, 16), dim3(512), 0, stream>>>(xb, wqkv_t, bqkv, qkv, N_TOK, 3072, 1024);
    attn_mfma<<<dim3(SEQ_L / 128, 32), dim3(512), 0, stream>>>(qkv, ao);
    gemm_pipe128<0><<<dim3(8, 32, 2), dim3(512), 0, stream>>>(ao, wm_t, bm, msg, N_TOK, 1024, 1024);
    add_ln<0, 1, 0, 1><<<dim3(N_TOK), blk, 0, stream>>>(x, msg, msg2, g1, be1, nullptr, hb);
    gemm_pipe<1><<<dim3(16, 16), dim3(512), 0, stream>>>(hb, w1_t, b1, f1, N_TOK, FF_DIM, 1024);
    gemm_pipe128<0><<<dim3(8, 32, 1), dim3(512), 0, stream>>>(f1, w2_t, b2, ffn, N_TOK, 1024, FF_DIM);
    add_ln<1, 0, 1, 0><<<dim3(N_TOK), blk, 0, stream>>>(hb, ffn, nullptr, g2, be2, out, nullptr);
}

// Round 13
// 227.706 us; speedup vs baseline: 1.1698x; 1.0946x over previous
//
#include <hip/hip_runtime.h>

#define D_MODEL 1024
#define N_TOK   4096
#define HEADS   16
#define FF_DIM  4096
#define SEQ_L   2048

typedef unsigned short u16;
typedef unsigned int   u32;
typedef __bf16 bf16x8 __attribute__((ext_vector_type(8)));
typedef float  f32x4  __attribute__((ext_vector_type(4)));

#define AS1C(p) ((const __attribute__((address_space(1))) void*)(p))
#define AS3(p)  ((__attribute__((address_space(3))) void*)(p))

__device__ __forceinline__ u16 f2bf(float f) {
    union { float f; unsigned u; } c; c.f = f;
    return (u16)((c.u + 0x7fffu + ((c.u >> 16) & 1u)) >> 16);   // RNE
}
__device__ __forceinline__ float bf2f(u16 b) {
    union { unsigned u; float f; } c; c.u = ((unsigned)b) << 16;
    return c.f;
}
__device__ __forceinline__ u32 cvt_pk_bf16(float lo, float hi) {
    u32 r;
    asm("v_cvt_pk_bf16_f32 %0, %1, %2" : "=v"(r) : "v"(lo), "v"(hi));
    return r;
}
__device__ __forceinline__ float fmax3(float a, float b, float c) {
    float r;
    asm("v_max3_f32 %0, %1, %2, %3" : "=v"(r) : "v"(a), "v"(b), "v"(c));
    return r;
}

// ---------------------------------------------------------------------------
// Pipelined 256x256 GEMM (counted-vmcnt, 4 phases/K-tile, double-buffer LDS).
// 512 thr = 8 waves (2M x 4N), wave tile 128x64. XCD-swizzled grid.
// ---------------------------------------------------------------------------
template<int RELU>
__global__ __launch_bounds__(512, 2)
void gemm_pipe(const u16* __restrict__ A, const u16* __restrict__ Bt,
               const float* __restrict__ bias, u16* __restrict__ C,
               int M, int N, int K)
{
    __shared__ u16 As[2][256 * 64];
    __shared__ u16 Bs[2][256 * 64];

    const int tid = threadIdx.x;
    const int wid = tid >> 6, lane = tid & 63;
    const int wr  = wid >> 2, wc = wid & 3;
    const int l15 = lane & 15, l16 = lane >> 4;

    const int nwg = gridDim.x * gridDim.y;
    int bid = blockIdx.y * gridDim.x + blockIdx.x;
    bid = (bid & 7) * (nwg >> 3) + (bid >> 3);
    const int r0 = (bid / gridDim.x) * 256, c0 = (bid % gridDim.x) * 256;

    const u16* Ab = A  + (size_t)r0 * K;
    const u16* Bb = Bt + (size_t)c0 * K;

    f32x4 acc[8][4];
#pragma unroll
    for (int m = 0; m < 8; ++m)
#pragma unroll
        for (int n = 0; n < 4; ++n) acc[m][n] = (f32x4){0.f, 0.f, 0.f, 0.f};

    auto stage = [&](u16* dst, const u16* src, int kbase) {
#pragma unroll
        for (int i = 0; i < 4; ++i) {
            const int r  = i * 64 + (tid >> 3);
            const int gc = (tid & 7) ^ (r & 7);
            __builtin_amdgcn_global_load_lds(AS1C(src + (size_t)r * K + kbase + gc * 8),
                                             AS3(dst + (i * 64 + (wid << 3)) * 64), 16, 0, 0);
        }
    };

    bf16x8 af[4][2], bbA[2][2], bbB[2][2];

    auto ldAf = [&](const u16* sl, int mh) {
#pragma unroll
        for (int m = 0; m < 4; ++m) {
            const int row = wr * 128 + (mh * 4 + m) * 16 + l15;
#pragma unroll
            for (int ks = 0; ks < 2; ++ks) {
                const int ch = (ks * 4 + l16) ^ (row & 7);
                af[m][ks] = *(const bf16x8*)&sl[row * 64 + ch * 8];
            }
        }
    };
    auto ldBf = [&](const u16* sl, int pair, bf16x8 (&bb)[2][2]) {
#pragma unroll
        for (int n = 0; n < 2; ++n) {
            const int row = wc * 64 + (pair * 2 + n) * 16 + l15;
#pragma unroll
            for (int ks = 0; ks < 2; ++ks) {
                const int ch = (ks * 4 + l16) ^ (row & 7);
                bb[n][ks] = *(const bf16x8*)&sl[row * 64 + ch * 8];
            }
        }
    };
    auto mm16 = [&](int mh, int pair, bf16x8 (&bb)[2][2]) {
        __builtin_amdgcn_s_setprio(1);
#pragma unroll
        for (int ks = 0; ks < 2; ++ks)
#pragma unroll
            for (int m = 0; m < 4; ++m)
#pragma unroll
                for (int n = 0; n < 2; ++n)
                    acc[mh * 4 + m][pair * 2 + n] =
                        __builtin_amdgcn_mfma_f32_16x16x32_bf16(af[m][ks], bb[n][ks],
                                                                acc[mh * 4 + m][pair * 2 + n], 0, 0, 0);
        __builtin_amdgcn_s_setprio(0);
    };

    const int nt = K >> 6;
    stage(&As[0][0], Ab, 0);
    stage(&Bs[0][0], Bb, 0);
    stage(&As[1][0], Ab, 64);

    for (int t = 0; t < nt; ++t) {
        u16* Asl = &As[t & 1][0];
        u16* Bsl = &Bs[t & 1][0];
        u16* Aso = &As[t & 1][0];
        u16* Bso = &Bs[(t + 1) & 1][0];

        if (t + 1 < nt) { asm volatile("s_waitcnt vmcnt(4)" ::: "memory"); }
        else            { asm volatile("s_waitcnt vmcnt(0)" ::: "memory"); }
        __builtin_amdgcn_s_barrier();
        ldAf(Asl, 0);
        ldBf(Bsl, 0, bbA);
        if (t + 1 < nt) stage(Bso, Bb, (t + 1) * 64);
        __builtin_amdgcn_s_barrier();
        mm16(0, 0, bbA);
        __builtin_amdgcn_s_barrier();
        ldBf(Bsl, 1, bbB);
        mm16(0, 1, bbB);
        __builtin_amdgcn_s_barrier();
        ldAf(Asl, 1);
        mm16(1, 0, bbA);
        __builtin_amdgcn_s_barrier();
        if (t + 2 < nt) stage(Aso, Ab, (t + 2) * 64);
        mm16(1, 1, bbB);
        __builtin_amdgcn_s_barrier();
    }

#pragma unroll
    for (int n = 0; n < 4; ++n) {
        const int col = c0 + wc * 64 + n * 16 + l15;
        const float bv = bias[col];
#pragma unroll
        for (int m = 0; m < 8; ++m) {
#pragma unroll
            for (int r = 0; r < 4; ++r) {
                const size_t row = (size_t)(r0 + wr * 128 + m * 16 + l16 * 4 + r);
                float v = acc[m][n][r] + bv;
                if (RELU) v = fmaxf(v, 0.f);
                C[row * N + col] = f2bf(v);
            }
        }
    }
}

// ---------------------------------------------------------------------------
// Pipelined 128x128 GEMM with SPLIT-K over blockIdx.z: each z computes K/nz
// and writes a bf16 partial to C + z*M*N (bias only in z==0).
// ---------------------------------------------------------------------------
template<int RELU>
__global__ __launch_bounds__(512, 2)
void gemm_pipe128(const u16* __restrict__ A, const u16* __restrict__ Bt,
                  const float* __restrict__ bias, u16* __restrict__ C,
                  int M, int N, int K)
{
    __shared__ u16 As[2][128 * 64];
    __shared__ u16 Bs[2][128 * 64];

    const int tid = threadIdx.x;
    const int wid = tid >> 6, lane = tid & 63;
    const int wr  = wid >> 2, wc = wid & 3;
    const int l15 = lane & 15, l16 = lane >> 4;

    const int nwg = gridDim.x * gridDim.y;
    int bid = blockIdx.y * gridDim.x + blockIdx.x;
    bid = (bid & 7) * (nwg >> 3) + (bid >> 3);
    const int r0 = (bid / gridDim.x) * 128, c0 = (bid % gridDim.x) * 128;

    const int Ks   = K / gridDim.z;
    const int koff = blockIdx.z * Ks;

    const u16* Ab = A  + (size_t)r0 * K + koff;
    const u16* Bb = Bt + (size_t)c0 * K + koff;
    u16*       Cs = C  + (size_t)blockIdx.z * M * N;

    f32x4 acc[4][2];
#pragma unroll
    for (int m = 0; m < 4; ++m)
#pragma unroll
        for (int n = 0; n < 2; ++n) acc[m][n] = (f32x4){0.f, 0.f, 0.f, 0.f};

    auto stage = [&](u16* dst, const u16* src, int kbase) {
#pragma unroll
        for (int i = 0; i < 2; ++i) {
            const int r  = i * 64 + (tid >> 3);
            const int gc = (tid & 7) ^ (r & 7);
            __builtin_amdgcn_global_load_lds(AS1C(src + (size_t)r * K + kbase + gc * 8),
                                             AS3(dst + (i * 64 + (wid << 3)) * 64), 16, 0, 0);
        }
    };

    const int nt = Ks >> 6;
    stage(&As[0][0], Ab, 0);  stage(&Bs[0][0], Bb, 0);
    stage(&As[1][0], Ab, 64); stage(&Bs[1][0], Bb, 64);

    for (int t = 0; t < nt; ++t) {
        const u16* Asl = &As[t & 1][0];
        const u16* Bsl = &Bs[t & 1][0];

        if (t + 1 < nt) { asm volatile("s_waitcnt vmcnt(4)" ::: "memory"); }
        else            { asm volatile("s_waitcnt vmcnt(0)" ::: "memory"); }
        __builtin_amdgcn_s_barrier();

        bf16x8 af[4][2], bb[2][2];
#pragma unroll
        for (int m = 0; m < 4; ++m) {
            const int row = wr * 64 + m * 16 + l15;
#pragma unroll
            for (int ks = 0; ks < 2; ++ks) {
                const int ch = (ks * 4 + l16) ^ (row & 7);
                af[m][ks] = *(const bf16x8*)&Asl[row * 64 + ch * 8];
            }
        }
#pragma unroll
        for (int n = 0; n < 2; ++n) {
            const int row = wc * 32 + n * 16 + l15;
#pragma unroll
            for (int ks = 0; ks < 2; ++ks) {
                const int ch = (ks * 4 + l16) ^ (row & 7);
                bb[n][ks] = *(const bf16x8*)&Bsl[row * 64 + ch * 8];
            }
        }
        __builtin_amdgcn_s_setprio(1);
#pragma unroll
        for (int ks = 0; ks < 2; ++ks)
#pragma unroll
            for (int m = 0; m < 4; ++m)
#pragma unroll
                for (int n = 0; n < 2; ++n)
                    acc[m][n] = __builtin_amdgcn_mfma_f32_16x16x32_bf16(af[m][ks], bb[n][ks], acc[m][n], 0, 0, 0);
        __builtin_amdgcn_s_setprio(0);
        __builtin_amdgcn_s_barrier();

        if (t + 2 < nt) {
            stage(&As[t & 1][0], Ab, (t + 2) * 64);
            stage(&Bs[t & 1][0], Bb, (t + 2) * 64);
        }
    }

    const int addb = (blockIdx.z == 0);
#pragma unroll
    for (int n = 0; n < 2; ++n) {
        const int col = c0 + wc * 32 + n * 16 + l15;
        const float bv = addb ? bias[col] : 0.f;
#pragma unroll
        for (int m = 0; m < 4; ++m) {
#pragma unroll
            for (int r = 0; r < 4; ++r) {
                const size_t row = (size_t)(r0 + wr * 64 + m * 16 + l16 * 4 + r);
                float v = acc[m][n][r] + bv;
                if (RELU) v = fmaxf(v, 0.f);
                Cs[row * N + col] = f2bf(v);
            }
        }
    }
}

// ---------------------------------------------------------------------------
// MFMA flash attention v10: r9 structure + "-m baked into QK^T accumulator"
// (sacc initialized to -m_c -> MFMA emits S-m; no per-element v_sub).
// Shifted-domain defer-max: m_c starts at 0; rescale subtracts d=max(mx,0).
// ---------------------------------------------------------------------------
__global__ __launch_bounds__(512, 4)
void attn_mfma(const u16* __restrict__ qkv, u16* __restrict__ ao)
{
    __shared__ u16 Kl[2][128 * 64];   // [s][d] bf16, chunk^(s&7) swizzle
    __shared__ u32 Vt[64 * 64];       // [d][s/2] packed, word^mask(d) swizzle

    const int tid = threadIdx.x;
    const int wid = tid >> 6, lane = tid & 63;
    const int l15 = lane & 15, l16 = lane >> 4;

    int lin = blockIdx.y * gridDim.x + blockIdx.x;       // 512 blocks
    lin = (lin & 7) * 64 + (lin >> 3);
    const int bh = lin >> 4, b = bh >> 4, h = bh & 15;
    const int q0 = (lin & 15) * 128;
    const int ho = h * 64;
    const size_t tb = (size_t)b * SEQ_L;

    const u16* qg = qkv + (tb + q0) * 3072 + ho;
    const u16* kg = qkv + tb * 3072 + 1024 + ho;
    const u16* vg = qkv + tb * 3072 + 2048 + ho;

    const float SC = 0.18033688f;     // (1/8) * log2(e)

    bf16x8 qa[2];
#pragma unroll
    for (int ks = 0; ks < 2; ++ks) {
        union { bf16x8 v; u16 u[8]; u32 w[4]; } a, r;
        a.v = *(const bf16x8*)(qg + (size_t)(wid * 16 + l15) * 3072 + ks * 32 + l16 * 8);
#pragma unroll
        for (int e = 0; e < 4; ++e)
            r.w[e] = cvt_pk_bf16(bf2f(a.u[2 * e]) * SC, bf2f(a.u[2 * e + 1]) * SC);
        qa[ks] = r.v;
    }

    union { bf16x8 v; u32 u[4]; } onesv;
#pragma unroll
    for (int e = 0; e < 4; ++e) onesv.u[e] = 0x3F803F80u;   // bf16 1.0 pairs

    const int sp = lane;
    const int dc = wid;

    auto stageK = [&](int buf, int s0) {
#pragma unroll
        for (int i = 0; i < 2; ++i) {
            const int r  = i * 64 + (tid >> 3);
            const int gc = (tid & 7) ^ (r & 7);
            __builtin_amdgcn_global_load_lds(AS1C(kg + (size_t)(s0 + r) * 3072 + gc * 8),
                                             AS3(&Kl[buf][(i * 64 + wid * 8) * 64]), 16, 0, 0);
        }
    };

    f32x4 oacc[4];
#pragma unroll
    for (int f = 0; f < 4; ++f) oacc[f] = (f32x4){0.f, 0.f, 0.f, 0.f};
    f32x4 lcol = (f32x4){0.f, 0.f, 0.f, 0.f};
    float m_c = 0.f;                  // shifted-domain running max (per q=l15)

    union { bf16x8 v; u16 u[8]; } ua, ub;
    stageK(0, 0);
    ua.v = *(const bf16x8*)(vg + (size_t)(2 * sp) * 3072 + dc * 8);
    ub.v = *(const bf16x8*)(vg + (size_t)(2 * sp + 1) * 3072 + dc * 8);

    const int nt = SEQ_L / 128;
    for (int t = 0; t < nt; ++t) {
        const int buf = t & 1;

        asm volatile("s_waitcnt vmcnt(0)" ::: "memory");
#pragma unroll
        for (int e = 0; e < 8; ++e) {
            const int d = dc * 8 + e;
            const int w = sp ^ (((d & 7) << 2) ^ ((d >> 3) << 1));
            Vt[d * 64 + w] = (u32)ua.u[e] | ((u32)ub.u[e] << 16);
        }
        __syncthreads();                               // barrier-1: K(t),V(t) visible

        if (t + 1 < nt) {                              // prefetch under compute
            stageK(buf ^ 1, (t + 1) * 128);
            ua.v = *(const bf16x8*)(vg + (size_t)((t + 1) * 128 + 2 * sp) * 3072 + dc * 8);
            ub.v = *(const bf16x8*)(vg + (size_t)((t + 1) * 128 + 2 * sp + 1) * 3072 + dc * 8);
        }

        // S^T - m  =  K Q^T accumulated onto C = -m_c  (per-lane q=l15)
        const float nm = -m_c;
        const f32x4 minit = (f32x4){nm, nm, nm, nm};
        f32x4 sacc[8];
#pragma unroll
        for (int f = 0; f < 8; ++f) sacc[f] = minit;
        __builtin_amdgcn_s_setprio(1);
#pragma unroll
        for (int ks = 0; ks < 2; ++ks)
#pragma unroll
            for (int f = 0; f < 8; ++f) {
                const int row = f * 16 + l15;
                const int ch  = (ks * 4 + l16) ^ (row & 7);
                bf16x8 kb = *(const bf16x8*)&Kl[buf][row * 64 + ch * 8];
                sacc[f] = __builtin_amdgcn_mfma_f32_16x16x32_bf16(kb, qa[ks], sacc[f], 0, 0, 0);
            }
        __builtin_amdgcn_s_setprio(0);

        // tile max in shifted domain
        float pm[8];
#pragma unroll
        for (int f = 0; f < 8; ++f)
            pm[f] = fmaxf(fmax3(sacc[f][0], sacc[f][1], sacc[f][2]), sacc[f][3]);
        float mx;
        {
            float t0 = fmax3(pm[0], pm[1], pm[2]);
            float t1 = fmax3(pm[3], pm[4], pm[5]);
            float t2 = fmaxf(pm[6], pm[7]);
            mx = fmax3(t0, t1, t2);
        }
        mx = fmaxf(mx, __shfl_xor(mx, 16));
        mx = fmaxf(mx, __shfl_xor(mx, 32));

        if (__any(mx > 8.f)) {                         // defer-max (shifted)
            const float d  = fmaxf(mx, 0.f);           // m_new - m_old, per q=l15
            const float cr0 = __builtin_exp2f(-d);
            m_c += d;
#pragma unroll
            for (int f = 0; f < 8; ++f)
#pragma unroll
                for (int r = 0; r < 4; ++r) sacc[f][r] -= d;
#pragma unroll
            for (int r = 0; r < 4; ++r) {
                const float cr = __shfl(cr0, l16 * 4 + r);
                lcol[r] *= cr;
#pragma unroll
                for (int f = 0; f < 4; ++f) oacc[f][r] *= cr;
            }
        }

#pragma unroll
        for (int f = 0; f < 8; ++f)
#pragma unroll
            for (int r = 0; r < 4; ++r)
                sacc[f][r] = __builtin_exp2f(sacc[f][r]);

        u32 pk[8][2];
#pragma unroll
        for (int f = 0; f < 8; ++f) {
            pk[f][0] = cvt_pk_bf16(sacc[f][0], sacc[f][1]);
            pk[f][1] = cvt_pk_bf16(sacc[f][2], sacc[f][3]);
        }

        // O += P V (+ l via ones column), k-order sigma
        __builtin_amdgcn_s_setprio(1);
#pragma unroll
        for (int S = 0; S < 4; ++S) {
            union { bf16x8 v; u32 u[4]; } af;
            af.u[0] = pk[2 * S][0];     af.u[1] = pk[2 * S][1];
            af.u[2] = pk[2 * S + 1][0]; af.u[3] = pk[2 * S + 1][1];
#pragma unroll
            for (int f2 = 0; f2 < 4; ++f2) {
                const int d = f2 * 16 + l15;
                const int swzd = ((d & 7) << 2) ^ ((d >> 3) << 1);
                union { bf16x8 v; uint2 u[2]; } vb;
                vb.u[0] = *(const uint2*)&Vt[d * 64 + ((16 * S + 2 * l16) ^ swzd)];
                vb.u[1] = *(const uint2*)&Vt[d * 64 + ((16 * S + 8 + 2 * l16) ^ swzd)];
                oacc[f2] = __builtin_amdgcn_mfma_f32_16x16x32_bf16(af.v, vb.v, oacc[f2], 0, 0, 0);
            }
            lcol = __builtin_amdgcn_mfma_f32_16x16x32_bf16(af.v, onesv.v, lcol, 0, 0, 0);
        }
        __builtin_amdgcn_s_setprio(0);
        __syncthreads();                               // barrier-2: tile consumed
    }

#pragma unroll
    for (int r = 0; r < 4; ++r) {
        const float inv = 1.f / lcol[r];
        const size_t row = tb + q0 + wid * 16 + l16 * 4 + r;
#pragma unroll
        for (int f2 = 0; f2 < 4; ++f2)
            ao[row * 1024 + ho + f2 * 16 + l15] = f2bf(oacc[f2][r] * inv);
    }
}

// ---------------------------------------------------------------------------
// Fused residual add + LayerNorm.
//   WF: f32 out, WB: bf16 out, XBF: residual is bf16, Y2: sum two y partials.
// ---------------------------------------------------------------------------
template<int WF, int WB, int XBF, int Y2>
__global__ __launch_bounds__(256)
void add_ln(const void* __restrict__ xv, const u16* __restrict__ y,
            const u16* __restrict__ y2,
            const float* __restrict__ g, const float* __restrict__ be,
            float* __restrict__ outf, u16* __restrict__ outb)
{
    __shared__ float red[4];
    const int t = blockIdx.x, tid = threadIdx.x;
    const int c = tid * 4, lane = tid & 63, wv = tid >> 6;

    float xs[4];
    if (XBF) {
        ushort4 a = *(const ushort4*)((const u16*)xv + (size_t)t * D_MODEL + c);
        xs[0] = bf2f(a.x); xs[1] = bf2f(a.y); xs[2] = bf2f(a.z); xs[3] = bf2f(a.w);
    } else {
        float4 a = *(const float4*)((const float*)xv + (size_t)t * D_MODEL + c);
        xs[0] = a.x; xs[1] = a.y; xs[2] = a.z; xs[3] = a.w;
    }
    ushort4 yb = *(const ushort4*)(y + (size_t)t * D_MODEL + c);
    float s[4] = {xs[0] + bf2f(yb.x), xs[1] + bf2f(yb.y),
                  xs[2] + bf2f(yb.z), xs[3] + bf2f(yb.w)};
    if (Y2) {
        ushort4 y2b = *(const ushort4*)(y2 + (size_t)t * D_MODEL + c);
        s[0] += bf2f(y2b.x); s[1] += bf2f(y2b.y);
        s[2] += bf2f(y2b.z); s[3] += bf2f(y2b.w);
    }

    float ps = s[0] + s[1] + s[2] + s[3];
#pragma unroll
    for (int off = 32; off > 0; off >>= 1) ps += __shfl_down(ps, off);
    if (lane == 0) red[wv] = ps;
    __syncthreads();
    const float mean = (red[0] + red[1] + red[2] + red[3]) * (1.f / D_MODEL);
    __syncthreads();

    float pv = 0.f;
#pragma unroll
    for (int u = 0; u < 4; ++u) { float d = s[u] - mean; pv += d * d; }
#pragma unroll
    for (int off = 32; off > 0; off >>= 1) pv += __shfl_down(pv, off);
    if (lane == 0) red[wv] = pv;
    __syncthreads();
    const float var = (red[0] + red[1] + red[2] + red[3]) * (1.f / D_MODEL);
    const float inv = rsqrtf(var + 1e-5f);

    float4 g4 = *(const float4*)(g + c);
    float4 b4 = *(const float4*)(be + c);
    float o[4];
#pragma unroll
    for (int u = 0; u < 4; ++u) o[u] = (s[u] - mean) * inv;
    float4 of = {o[0] * g4.x + b4.x, o[1] * g4.y + b4.y, o[2] * g4.z + b4.z, o[3] * g4.w + b4.w};
    if (WF) *(float4*)(outf + (size_t)t * D_MODEL + c) = of;
    if (WB) {
        ushort4 ob = {f2bf(of.x), f2bf(of.y), f2bf(of.z), f2bf(of.w)};
        *(ushort4*)(outb + (size_t)t * D_MODEL + c) = ob;
    }
}

// ---------------------------------------------------------------------------
// Merged preprocessing (unchanged).
// ---------------------------------------------------------------------------
__global__ __launch_bounds__(256)
void prep(const float* __restrict__ Wq, const float* __restrict__ Wk,
          const float* __restrict__ Wv, const float* __restrict__ Wm,
          const float* __restrict__ W1, const float* __restrict__ W2,
          const float* __restrict__ x,
          const float* __restrict__ bq, const float* __restrict__ bk,
          const float* __restrict__ bv,
          u16* __restrict__ wqkv_t, u16* __restrict__ wm_t,
          u16* __restrict__ w1_t, u16* __restrict__ w2_t,
          u16* __restrict__ xb, float* __restrict__ bqkv)
{
    const int blk = blockIdx.x, tid = threadIdx.x;
    if (blk < 3072) {
        __shared__ float T[64][65];
        const float* src; u16* dst; int K, N, tile;
        if (blk < 256)       { src = Wq; dst = wqkv_t;               K = 1024; N = 1024; tile = blk; }
        else if (blk < 512)  { src = Wk; dst = wqkv_t + 1024 * 1024; K = 1024; N = 1024; tile = blk - 256; }
        else if (blk < 768)  { src = Wv; dst = wqkv_t + 2*1024*1024; K = 1024; N = 1024; tile = blk - 512; }
        else if (blk < 1024) { src = Wm; dst = wm_t;                 K = 1024; N = 1024; tile = blk - 768; }
        else if (blk < 2048) { src = W1; dst = w1_t;                 K = 1024; N = 4096; tile = blk - 1024; }
        else                 { src = W2; dst = w2_t;                 K = 4096; N = 1024; tile = blk - 2048; }
        const int ntn = N >> 6;
        const int n0 = (tile % ntn) * 64, k0 = (tile / ntn) * 64;
        const int rr = tid >> 4, cc = (tid & 15) * 4;
#pragma unroll
        for (int u = 0; u < 4; ++u) {
            const float4 v = *(const float4*)(src + (size_t)(k0 + rr + u * 16) * N + n0 + cc);
            T[rr + u * 16][cc + 0] = v.x; T[rr + u * 16][cc + 1] = v.y;
            T[rr + u * 16][cc + 2] = v.z; T[rr + u * 16][cc + 3] = v.w;
        }
        __syncthreads();
#pragma unroll
        for (int u = 0; u < 4; ++u) {
            const int n = rr + u * 16;
            ushort4 o;
            o.x = f2bf(T[cc + 0][n]); o.y = f2bf(T[cc + 1][n]);
            o.z = f2bf(T[cc + 2][n]); o.w = f2bf(T[cc + 3][n]);
            *(ushort4*)(dst + (size_t)(n0 + n) * K + k0 + cc) = o;
        }
    } else if (blk < 3072 + 4096) {
        const int i = (blk - 3072) * 1024 + tid * 4;
        float4 v = *(const float4*)(x + i);
        ushort4 o = {f2bf(v.x), f2bf(v.y), f2bf(v.z), f2bf(v.w)};
        *(ushort4*)(xb + i) = o;
    } else {
#pragma unroll
        for (int u = 0; u < 12; ++u) {
            const int i = u * 256 + tid;
            bqkv[i] = i < 1024 ? bq[i] : (i < 2048 ? bk[i - 1024] : bv[i - 2048]);
        }
    }
}

// ---------------------------------------------------------------------------
extern "C" void kernel_launch(void* const* d_in, const int* in_sizes, int n_in,
                              void* d_out, int out_size, void* d_ws, size_t ws_size,
                              hipStream_t stream)
{
    (void)in_sizes; (void)n_in; (void)out_size; (void)ws_size;

    const float* x   = (const float*)d_in[0];
    const float* Wq  = (const float*)d_in[1];
    const float* bq  = (const float*)d_in[2];
    const float* Wk  = (const float*)d_in[3];
    const float* bk  = (const float*)d_in[4];
    const float* Wv  = (const float*)d_in[5];
    const float* bv  = (const float*)d_in[6];
    const float* Wm  = (const float*)d_in[7];
    const float* bm  = (const float*)d_in[8];
    const float* W1  = (const float*)d_in[9];
    const float* b1  = (const float*)d_in[10];
    const float* W2  = (const float*)d_in[11];
    const float* b2  = (const float*)d_in[12];
    const float* g1  = (const float*)d_in[13];
    const float* be1 = (const float*)d_in[14];
    const float* g2  = (const float*)d_in[15];
    const float* be2 = (const float*)d_in[16];
    float* out = (float*)d_out;

    char* base = (char*)d_ws;
    const size_t MB = 1u << 20;
    u16*   wqkv_t = (u16*)(base);              //  0..6MB : [3072][1024]
    u16*   wm_t   = (u16*)(base + 6 * MB);     //  6..8MB
    u16*   w1_t   = (u16*)(base + 8 * MB);     //  8..16MB: [4096][1024]
    u16*   w2_t   = (u16*)(base + 16 * MB);    // 16..24MB: [1024][4096]
    float* bqkv   = (float*)(base + 24 * MB);
    u16*   xb     = (u16*)(base + 25 * MB);    // 25..33MB (dead after QKV)
    u16*   qkv    = (u16*)(base + 33 * MB);    // 33..57MB [4096][3072]
    u16*   ao     = (u16*)(base + 57 * MB);    // 57..65MB
    u16*   msg    = (u16*)(base + 25 * MB);    // Wm partial0 (z1 lands at 33MB)
    u16*   f1     = (u16*)(base + 33 * MB);    // FFN1 out 33..65MB (post-LN1)
    u16*   hb     = (u16*)(base + 65 * MB);    // 65..73MB
    u16*   ffn    = (u16*)(base + 73 * MB);    // FFN2 partial0 73..81, z1 81..89
    dim3 blk(256);
    prep<<<dim3(3072 + 4096 + 1), blk, 0, stream>>>(Wq, Wk, Wv, Wm, W1, W2, x,
                                                    bq, bk, bv,
                                                    wqkv_t, wm_t, w1_t, w2_t, xb, bqkv);

    gemm_pipe<0><<<dim3(12, 16), dim3(512), 0, stream>>>(xb, wqkv_t, bqkv, qkv, N_TOK, 3072, 1024);
    attn_mfma<<<dim3(SEQ_L / 128, 32), dim3(512), 0, stream>>>(qkv, ao);
    gemm_pipe128<0><<<dim3(8, 32, 2), dim3(512), 0, stream>>>(ao, wm_t, bm, msg, N_TOK, 1024, 1024);
    add_ln<0, 1, 0, 1><<<dim3(N_TOK), blk, 0, stream>>>(x, msg, msg + (size_t)N_TOK * 1024,
                                                        g1, be1, nullptr, hb);
    gemm_pipe<1><<<dim3(16, 16), dim3(512), 0, stream>>>(hb, w1_t, b1, f1, N_TOK, FF_DIM, 1024);
    gemm_pipe128<0><<<dim3(8, 32, 2), dim3(512), 0, stream>>>(f1, w2_t, b2, ffn, N_TOK, 1024, FF_DIM);
    add_ln<1, 0, 1, 1><<<dim3(N_TOK), blk, 0, stream>>>(hb, ffn, ffn + (size_t)N_TOK * 1024,
                                                        g2, be2, out, nullptr);
}